// Round 1
// 893.815 us; speedup vs baseline: 1.1343x; 1.1343x over previous
//
#include <hip/hip_runtime.h>
#include <math.h>

#define T_TOK 4096
#define H_DIM 1024
#define I_DIM 4096
#define E_NUM 8

// All staged bf16 matrices live in "panels": for matrix M[R][K],
//   panel(rb, kt, half) = rows [rb*256 + half*128, +128) x k [kt*64, +64)
// stored row-major [128][64] bf16 = 16 KiB, linear (NO swizzle in global).
// The st-swizzle byte^=((row&7)<<4) is applied at global_load_lds SOURCE
// address (LDS dest must be linear) and again on ds_read -> consistent.

typedef short s16x8 __attribute__((ext_vector_type(8)));
typedef float f32x4 __attribute__((ext_vector_type(4)));

__device__ __forceinline__ unsigned short f2b(float f) {
  union { float f; unsigned u; } v; v.f = f;
  unsigned r = v.u + 0x7fffu + ((v.u >> 16) & 1u);
  return (unsigned short)(r >> 16);
}

__device__ __forceinline__ void gld_lds16(short* lds, const short* g) {
  __builtin_amdgcn_global_load_lds(
      (const __attribute__((address_space(1))) void*)g,
      (__attribute__((address_space(3))) void*)lds, 16, 0, 0);
}

// Branch-free exact-GELU via A&S 7.1.25 3-term erf (|eps|<=2.5e-5).
__device__ __forceinline__ float gelu_f(float v) {
  float a = fabsf(v);
  float z = a * 0.70710678118f;
  float t = __builtin_amdgcn_rcpf(fmaf(0.47047f, z, 1.0f));
  float p = fmaf(fmaf(0.7478556f, t, -0.0958798f), t, 0.3480242f) * t;
  float e = __expf(-z * z);
  float erf_abs = fmaf(-p, e, 1.0f);
  return fmaf(0.5f * a, erf_abs, 0.5f * v);
}

// ---------- gate: softmax(x @ Wg^T), one wave per token ----------
__global__ __launch_bounds__(256) void gate_kernel(
    const float* __restrict__ x, const float* __restrict__ Wg,
    float* __restrict__ gate)
{
  int t = blockIdx.x * 4 + (threadIdx.x >> 6);
  int lane = threadIdx.x & 63;
  const float* xr = x + (size_t)t * H_DIM;
  float acc[E_NUM];
#pragma unroll
  for (int e = 0; e < E_NUM; ++e) acc[e] = 0.f;
  for (int j = 0; j < H_DIM / 64; ++j) {
    float xv = xr[lane + j * 64];
#pragma unroll
    for (int e = 0; e < E_NUM; ++e)
      acc[e] += xv * Wg[e * H_DIM + lane + j * 64];
  }
#pragma unroll
  for (int e = 0; e < E_NUM; ++e)
    for (int s = 32; s > 0; s >>= 1)
      acc[e] += __shfl_xor(acc[e], s, 64);
  if (lane == 0) {
    float mx = acc[0];
#pragma unroll
    for (int e = 1; e < E_NUM; ++e) mx = fmaxf(mx, acc[e]);
    float sum = 0.f, ex[E_NUM];
#pragma unroll
    for (int e = 0; e < E_NUM; ++e) { ex[e] = expf(acc[e] - mx); sum += ex[e]; }
    float inv = 1.f / sum;
#pragma unroll
    for (int e = 0; e < E_NUM; ++e) gate[t * E_NUM + e] = ex[e] * inv;
  }
}

// ---------- x fp32 -> xb panels [rb=t/256][kt=h/64][half][128][64] ----------
__global__ __launch_bounds__(256) void convert_x_kernel(
    const float* __restrict__ x, short* __restrict__ xb)
{
  int idx = blockIdx.x * 256 + threadIdx.x;     // 524288 total
  int t = idx >> 7;
  int h0 = (idx & 127) << 3;
  const float* src = x + (size_t)t * H_DIM + h0;
  float4 a = *(const float4*)src;
  float4 b = *(const float4*)(src + 4);
  s16x8 v;
  v[0] = f2b(a.x); v[1] = f2b(a.y); v[2] = f2b(a.z); v[3] = f2b(a.w);
  v[4] = f2b(b.x); v[5] = f2b(b.y); v[6] = f2b(b.z); v[7] = f2b(b.w);
  int rb = t >> 8, kt = h0 >> 6, half = (t >> 7) & 1;
  size_t off = ((size_t)((rb * 16 + kt) * 2 + half)) * 8192
             + (size_t)(t & 127) * 64 + (h0 & 63);
  *(s16x8*)(xb + off) = v;
}

// ---------- W1 [E][H][I] -> W1t panels per e: rows=i, k=h ----------
__global__ __launch_bounds__(256) void trans_w1_kernel(
    const float* __restrict__ W1, short* __restrict__ W1t)
{
  __shared__ short tile[64][65];            // [h][i]
  const int e = blockIdx.z;
  const int i0 = blockIdx.x * 64, h0 = blockIdx.y * 64;
  const int tid = threadIdx.x, c = tid & 63, r0 = tid >> 6;
  const float* src = W1 + ((size_t)e * H_DIM + h0) * I_DIM + i0;
#pragma unroll
  for (int j = 0; j < 16; ++j) {
    int r = j * 4 + r0;
    tile[r][c] = f2b(src[(size_t)r * I_DIM + c]);
  }
  __syncthreads();
  const int i = tid & 63, kq = tid >> 6;
  const size_t base = ((size_t)((e * 16 + (i0 >> 8)) * 16 + (h0 >> 6)) * 2
                       + ((i0 >> 7) & 1)) * 8192
                    + (size_t)((i0 & 64) + i) * 64;
#pragma unroll
  for (int w = 0; w < 2; ++w) {
    int kcl = kq + w * 4;                    // h-chunk 0..7
    s16x8 v;
#pragma unroll
    for (int j = 0; j < 8; ++j) v[j] = tile[kcl * 8 + j][i];
    *(s16x8*)(W1t + base + kcl * 8) = v;
  }
}

// ---------- W2 [E][I][H] -> W2t panels: rows=h, k=e*I+i ----------
__global__ __launch_bounds__(256) void trans_w2_kernel(
    const float* __restrict__ W2, short* __restrict__ W2t)
{
  __shared__ short tile[64][65];            // [i][h]
  const int e = blockIdx.z;
  const int i0 = blockIdx.x * 64, h0 = blockIdx.y * 64;
  const int tid = threadIdx.x, c = tid & 63, r0 = tid >> 6;
  const float* src = W2 + ((size_t)e * I_DIM + i0) * H_DIM + h0;
#pragma unroll
  for (int j = 0; j < 16; ++j) {
    int r = j * 4 + r0;
    tile[r][c] = f2b(src[(size_t)r * H_DIM + c]);
  }
  __syncthreads();
  const int h = tid & 63, kq = tid >> 6;
  const size_t base = ((size_t)((h0 >> 8) * 512 + e * 64 + (i0 >> 6)) * 2
                       + ((h0 >> 7) & 1)) * 8192
                    + (size_t)((h0 & 64) + h) * 64;
#pragma unroll
  for (int w = 0; w < 2; ++w) {
    int kcl = kq + w * 4;                    // i-chunk 0..7
    s16x8 v;
#pragma unroll
    for (int j = 0; j < 8; ++j) v[j] = tile[kcl * 8 + j][h];
    *(s16x8*)(W2t + base + kcl * 8) = v;
  }
}

// ================= 256x256xBK64 8-phase GEMM core =================
// 512 threads = 8 waves (2M x 4N); per-wave C = 128(M) x 64(N).
// LDS 128 KiB: A[2buf][2half][128][64] then B same at +64 KiB.
// Counted vmcnt(4) at phases 4/8 (never 0 mid-loop); raw s_barrier.

#define BARR()  __builtin_amdgcn_s_barrier()
#define FENCE() asm volatile("" ::: "memory")
#define LGKM0() do { asm volatile("s_waitcnt lgkmcnt(0)" ::: "memory"); \
                     __builtin_amdgcn_sched_barrier(0); } while (0)
#define VMC(N)  asm volatile("s_waitcnt vmcnt(" #N ")" ::: "memory")
#define PRIO1() __builtin_amdgcn_s_setprio(1)
#define PRIO0() __builtin_amdgcn_s_setprio(0)
#define SCHEDB() __builtin_amdgcn_sched_barrier(0)

__device__ __forceinline__ void gemm_core(
    const short* __restrict__ Ag, const short* __restrict__ Bg,
    int nk, short* lds, f32x4 acc[8][4])
{
  const int tid  = threadIdx.x;
  const int wave = tid >> 6, lane = tid & 63;
  const int wm = wave >> 2, wn = wave & 3;
  const int g = lane >> 4, r16 = lane & 15;

  // stage-source swizzled offsets (shorts): L ^ (((L>>7)&7)<<4)
  const int L0 = tid * 16;
  const int L1 = 8192 + tid * 16;
  const int s0 = (L0 ^ (((L0 >> 7) & 7) << 4)) >> 1;
  const int s1 = (L1 ^ (((L1 >> 7) & 7) << 4)) >> 1;

  short* stA = lds + wave * 512;            // per-wave 1 KiB slice
  short* stB = lds + 32768 + wave * 512;

  // ds_read per-lane offsets (shorts), same XOR swizzle
  const int xr_ = (r16 & 7) << 4;
  const int rd0 = r16 * 64 + ((((0 << 6) | (g << 4)) ^ xr_) >> 1);
  const int rd1 = r16 * 64 + ((((1 << 6) | (g << 4)) ^ xr_) >> 1);

  const short* Ah = lds + wm * 8192;
  const short* Bh = lds + 32768 + (wn >> 1) * 8192 + (wn & 1) * 4096;

  s16x8 af[16], bf0, bf1;

#define STAGE_A(KT, HH, BUF) do { \
    const short* _s = Ag + (size_t)(KT) * 16384 + (HH) * 8192; \
    short* _d = stA + ((BUF) * 2 + (HH)) * 8192; \
    gld_lds16(_d, _s + s0); \
    gld_lds16(_d + 4096, _s + s1); } while (0)
#define STAGE_B(KT, HH, BUF) do { \
    const short* _s = Bg + (size_t)(KT) * 16384 + (HH) * 8192; \
    short* _d = stB + ((BUF) * 2 + (HH)) * 8192; \
    gld_lds16(_d, _s + s0); \
    gld_lds16(_d + 4096, _s + s1); } while (0)
#define LDA(BUF) \
    _Pragma("unroll") \
    for (int mi = 0; mi < 8; ++mi) { \
      af[mi * 2]     = *(const s16x8*)(Ah + (BUF) * 16384 + mi * 1024 + rd0); \
      af[mi * 2 + 1] = *(const s16x8*)(Ah + (BUF) * 16384 + mi * 1024 + rd1); }
#define LDB(BUF, NL) do { \
    bf0 = *(const s16x8*)(Bh + (BUF) * 16384 + (NL) * 1024 + rd0); \
    bf1 = *(const s16x8*)(Bh + (BUF) * 16384 + (NL) * 1024 + rd1); } while (0)
#define MFMA_COL(NL) \
    _Pragma("unroll") \
    for (int mi = 0; mi < 8; ++mi) { \
      acc[mi][NL] = __builtin_amdgcn_mfma_f32_16x16x32_bf16(af[mi * 2], bf0, acc[mi][NL], 0, 0, 0); \
      acc[mi][NL] = __builtin_amdgcn_mfma_f32_16x16x32_bf16(af[mi * 2 + 1], bf1, acc[mi][NL], 0, 0, 0); }

  // prologue: K-tile 0 (A+B) + K-tile 1 (A); wait for K-tile 0 only.
  STAGE_A(0, 0, 0); STAGE_A(0, 1, 0); STAGE_B(0, 0, 0); STAGE_B(0, 1, 0);
  STAGE_A(1, 0, 1); STAGE_A(1, 1, 1);
  VMC(4);
  BARR(); FENCE();

  const int iters = nk >> 1;
  for (int it = 0; it < iters; ++it) {
    const int u = it * 2, v = u + 1;
    const bool nlast = (it + 1 < iters);

    // ---- K-tile u (buffer 0): phases 1-4 ----
    LDA(0); LDB(0, 0);
    STAGE_B(v, 0, 1);
    BARR(); LGKM0();
    PRIO1(); MFMA_COL(0); PRIO0();
    SCHEDB(); BARR(); FENCE();

    LDB(0, 1);
    STAGE_B(v, 1, 1);
    BARR(); LGKM0();
    PRIO1(); MFMA_COL(1); PRIO0();
    SCHEDB(); BARR(); FENCE();

    LDB(0, 2);
    if (nlast) STAGE_A(u + 2, 0, 0);
    BARR(); LGKM0();
    PRIO1(); MFMA_COL(2); PRIO0();
    SCHEDB(); BARR(); FENCE();

    LDB(0, 3);
    if (nlast) STAGE_A(u + 2, 1, 0);
    BARR(); LGKM0();
    PRIO1(); MFMA_COL(3); PRIO0();
    if (nlast) { VMC(4); } else { VMC(0); }   // K-tile v fully resident
    SCHEDB(); BARR(); FENCE();

    // ---- K-tile v (buffer 1): phases 5-8 ----
    LDA(1); LDB(1, 0);
    if (nlast) STAGE_B(u + 2, 0, 0);
    BARR(); LGKM0();
    PRIO1(); MFMA_COL(0); PRIO0();
    SCHEDB(); BARR(); FENCE();

    LDB(1, 1);
    if (nlast) STAGE_B(u + 2, 1, 0);
    BARR(); LGKM0();
    PRIO1(); MFMA_COL(1); PRIO0();
    SCHEDB(); BARR(); FENCE();

    LDB(1, 2);
    if (nlast) STAGE_A(v + 2, 0, 1);
    BARR(); LGKM0();
    PRIO1(); MFMA_COL(2); PRIO0();
    SCHEDB(); BARR(); FENCE();

    LDB(1, 3);
    if (nlast) STAGE_A(v + 2, 1, 1);
    BARR(); LGKM0();
    PRIO1(); MFMA_COL(3); PRIO0();
    if (nlast) VMC(4);                        // K-tile u+2 fully resident
    SCHEDB(); BARR(); FENCE();
  }
#undef STAGE_A
#undef STAGE_B
#undef LDA
#undef LDB
#undef MFMA_COL
}

// ---------- GEMM1: h = gelu(W1^T-tile x x-tile + b1) * gate -> hg panels ----------
// A = W1t (rows=i), B = xb (rows=t): D row = i (4 consecutive per lane).
__global__ __launch_bounds__(512) void gemm1_kernel(
    const short* __restrict__ xb, const short* __restrict__ W1t,
    const float* __restrict__ b1, const float* __restrict__ gate,
    short* __restrict__ hg)
{
  extern __shared__ short lds[];
  const int bi = blockIdx.x, bt = blockIdx.y, e = blockIdx.z;
  f32x4 acc[8][4];
#pragma unroll
  for (int i = 0; i < 8; ++i)
#pragma unroll
    for (int j = 0; j < 4; ++j) acc[i][j] = (f32x4){0.f, 0.f, 0.f, 0.f};

  const short* Ag = W1t + (size_t)(e * 16 + bi) * 16 * 16384;
  const short* Bg = xb + (size_t)bt * 16 * 16384;
  gemm_core(Ag, Bg, 16, lds, acc);

  const int tid = threadIdx.x, wave = tid >> 6, lane = tid & 63;
  const int wm = wave >> 2, wn = wave & 3, g = lane >> 4, r16 = lane & 15;
#pragma unroll
  for (int mg = 0; mg < 8; ++mg) {
    const int i4 = bi * 256 + wm * 128 + mg * 16 + g * 4;   // 4 consecutive i
    const float4 b1v = *(const float4*)(b1 + e * I_DIM + i4);
    const int kt = (e * I_DIM + i4) >> 6;
    const int c = i4 & 63;
    short* dst = hg + ((size_t)(bt * 512 + kt) * 2 + (wn >> 1)) * 8192 + c;
#pragma unroll
    for (int ng = 0; ng < 4; ++ng) {
      const int tl = wn * 64 + ng * 16 + r16;               // t within tile
      const float gt = gate[(bt * 256 + tl) * E_NUM + e];
      const float v0 = gelu_f(acc[mg][ng][0] + b1v.x) * gt;
      const float v1 = gelu_f(acc[mg][ng][1] + b1v.y) * gt;
      const float v2 = gelu_f(acc[mg][ng][2] + b1v.z) * gt;
      const float v3 = gelu_f(acc[mg][ng][3] + b1v.w) * gt;
      int2 pk;
      pk.x = (int)((unsigned)f2b(v0) | ((unsigned)f2b(v1) << 16));
      pk.y = (int)((unsigned)f2b(v2) | ((unsigned)f2b(v3) << 16));
      *(int2*)(dst + (size_t)(tl & 127) * 64) = pk;
    }
  }
}

// ---------- GEMM2: part[ks] = hg-tile @ W2-tile (split-K=4, no atomics) ----------
// A = W2t (rows=h), B = hg (rows=t): D row = h (float4 stores).
__global__ __launch_bounds__(512) void gemm2_kernel(
    const short* __restrict__ W2t, const short* __restrict__ hg,
    float* __restrict__ part)
{
  extern __shared__ short lds[];
  const int bh = blockIdx.x, bt = blockIdx.y, ks = blockIdx.z;
  f32x4 acc[8][4];
#pragma unroll
  for (int i = 0; i < 8; ++i)
#pragma unroll
    for (int j = 0; j < 4; ++j) acc[i][j] = (f32x4){0.f, 0.f, 0.f, 0.f};

  const short* Ag = W2t + (size_t)(bh * 512 + ks * 128) * 16384;
  const short* Bg = hg  + (size_t)(bt * 512 + ks * 128) * 16384;
  gemm_core(Ag, Bg, 128, lds, acc);

  const int tid = threadIdx.x, wave = tid >> 6, lane = tid & 63;
  const int wm = wave >> 2, wn = wave & 3, g = lane >> 4, r16 = lane & 15;
  float* dst = part + (size_t)ks * ((size_t)T_TOK * H_DIM);
#pragma unroll
  for (int mg = 0; mg < 8; ++mg) {
    const int h4 = bh * 256 + wm * 128 + mg * 16 + g * 4;   // 4 consecutive h
#pragma unroll
    for (int ng = 0; ng < 4; ++ng) {
      const int t = bt * 256 + wn * 64 + ng * 16 + r16;
      *(f32x4*)(dst + (size_t)t * H_DIM + h4) = acc[mg][ng];
    }
  }
}

// ---------- reduce: out = sum_ks part[ks] + sum_e gate*b2 ----------
__global__ __launch_bounds__(256) void reduce_kernel(
    const float* __restrict__ part, const float* __restrict__ gate,
    const float* __restrict__ b2, float* __restrict__ out)
{
  const int idx = blockIdx.x * 256 + threadIdx.x;   // 1M threads, float4 each
  const int t = idx >> 8;
  const int h4 = (idx & 255) << 2;
  const size_t off = (size_t)t * H_DIM + h4;
  const size_t SL = (size_t)T_TOK * H_DIM;
  float4 a0 = *(const float4*)(part + off);
  float4 a1 = *(const float4*)(part + SL + off);
  float4 a2 = *(const float4*)(part + 2 * SL + off);
  float4 a3 = *(const float4*)(part + 3 * SL + off);
  float sx = a0.x + a1.x + a2.x + a3.x;
  float sy = a0.y + a1.y + a2.y + a3.y;
  float sz = a0.z + a1.z + a2.z + a3.z;
  float sw = a0.w + a1.w + a2.w + a3.w;
#pragma unroll
  for (int e = 0; e < E_NUM; ++e) {
    const float gv = gate[t * E_NUM + e];
    const float4 bv = *(const float4*)(b2 + e * H_DIM + h4);
    sx = fmaf(gv, bv.x, sx); sy = fmaf(gv, bv.y, sy);
    sz = fmaf(gv, bv.z, sz); sw = fmaf(gv, bv.w, sw);
  }
  float4 r; r.x = sx; r.y = sy; r.z = sz; r.w = sw;
  *(float4*)(out + off) = r;
}

// ---------- launch ----------
extern "C" void kernel_launch(void* const* d_in, const int* in_sizes, int n_in,
                              void* d_out, int out_size, void* d_ws, size_t ws_size,
                              hipStream_t stream) {
  const float* x  = (const float*)d_in[0];
  const float* Wg = (const float*)d_in[1];
  const float* W1 = (const float*)d_in[2];
  const float* b1 = (const float*)d_in[3];
  const float* W2 = (const float*)d_in[4];
  const float* b2 = (const float*)d_in[5];
  float* out = (float*)d_out;

  char* ws = (char*)d_ws;
  float* gate = (float*)ws;                                    // 128 KiB
  short* xb   = (short*)(ws + 131072);                         // 8 MiB
  short* W1t  = (short*)(ws + 131072 + 8388608);               // 64 MiB
  short* W2t  = (short*)(ws + 131072 + 8388608 + 67108864);    // 64 MiB
  short* hg   = (short*)(ws + 131072 + 8388608 + 2 * 67108864);// 256 MiB
  // part aliases xb+W1t (both dead after gemm1): 64 MiB
  float* part = (float*)(ws + 131072);

  static bool attr_done = false;
  if (!attr_done) {
    hipFuncSetAttribute((const void*)gemm1_kernel,
                        hipFuncAttributeMaxDynamicSharedMemorySize, 131072);
    hipFuncSetAttribute((const void*)gemm2_kernel,
                        hipFuncAttributeMaxDynamicSharedMemorySize, 131072);
    attr_done = true;
  }

  gate_kernel<<<T_TOK / 4, 256, 0, stream>>>(x, Wg, gate);
  convert_x_kernel<<<2048, 256, 0, stream>>>(x, xb);
  trans_w1_kernel<<<dim3(I_DIM / 64, H_DIM / 64, E_NUM), 256, 0, stream>>>(W1, W1t);
  trans_w2_kernel<<<dim3(I_DIM / 64, H_DIM / 64, E_NUM), 256, 0, stream>>>(W2, W2t);
  gemm1_kernel<<<dim3(16, 16, 8), 512, 131072, stream>>>(xb, W1t, b1, gate, hg);
  gemm2_kernel<<<dim3(4, 16, 4), 512, 131072, stream>>>(W2t, hg, part);
  reduce_kernel<<<4096, 256, 0, stream>>>(part, gate, b2, out);
}

// Round 3
// 872.958 us; speedup vs baseline: 1.1614x; 1.0239x over previous
//
#include <hip/hip_runtime.h>
#include <math.h>

#define T_TOK 4096
#define H_DIM 1024
#define I_DIM 4096
#define E_NUM 8

// All staged bf16 matrices live in "panels": for matrix M[R][K],
//   panel(rb, kt, half) = rows [rb*256 + half*128, +128) x k [kt*64, +64)
// stored row-major [128][64] bf16 = 16 KiB, linear (NO swizzle in global).
// The st-swizzle byte^=((row&7)<<4) is applied at global_load_lds SOURCE
// address (LDS dest must be linear) and again on ds_read -> consistent.

typedef short s16x8 __attribute__((ext_vector_type(8)));
typedef float f32x4 __attribute__((ext_vector_type(4)));

__device__ __forceinline__ unsigned short f2b(float f) {
  union { float f; unsigned u; } v; v.f = f;
  unsigned r = v.u + 0x7fffu + ((v.u >> 16) & 1u);
  return (unsigned short)(r >> 16);
}

__device__ __forceinline__ void gld_lds16(short* lds, const short* g) {
  __builtin_amdgcn_global_load_lds(
      (const __attribute__((address_space(1))) void*)g,
      (__attribute__((address_space(3))) void*)lds, 16, 0, 0);
}

// Branch-free exact-GELU via A&S 7.1.25 3-term erf (|eps|<=2.5e-5).
__device__ __forceinline__ float gelu_f(float v) {
  float a = fabsf(v);
  float z = a * 0.70710678118f;
  float t = __builtin_amdgcn_rcpf(fmaf(0.47047f, z, 1.0f));
  float p = fmaf(fmaf(0.7478556f, t, -0.0958798f), t, 0.3480242f) * t;
  float e = __expf(-z * z);
  float erf_abs = fmaf(-p, e, 1.0f);
  return fmaf(0.5f * a, erf_abs, 0.5f * v);
}

// ---------- gate: softmax(x @ Wg^T), one wave per token ----------
__global__ __launch_bounds__(256) void gate_kernel(
    const float* __restrict__ x, const float* __restrict__ Wg,
    float* __restrict__ gate)
{
  int t = blockIdx.x * 4 + (threadIdx.x >> 6);
  int lane = threadIdx.x & 63;
  const float* xr = x + (size_t)t * H_DIM;
  float acc[E_NUM];
#pragma unroll
  for (int e = 0; e < E_NUM; ++e) acc[e] = 0.f;
  for (int j = 0; j < H_DIM / 64; ++j) {
    float xv = xr[lane + j * 64];
#pragma unroll
    for (int e = 0; e < E_NUM; ++e)
      acc[e] += xv * Wg[e * H_DIM + lane + j * 64];
  }
#pragma unroll
  for (int e = 0; e < E_NUM; ++e)
    for (int s = 32; s > 0; s >>= 1)
      acc[e] += __shfl_xor(acc[e], s, 64);
  if (lane == 0) {
    float mx = acc[0];
#pragma unroll
    for (int e = 1; e < E_NUM; ++e) mx = fmaxf(mx, acc[e]);
    float sum = 0.f, ex[E_NUM];
#pragma unroll
    for (int e = 0; e < E_NUM; ++e) { ex[e] = expf(acc[e] - mx); sum += ex[e]; }
    float inv = 1.f / sum;
#pragma unroll
    for (int e = 0; e < E_NUM; ++e) gate[t * E_NUM + e] = ex[e] * inv;
  }
}

// ---------- x fp32 -> xb panels [rb=t/256][kt=h/64][half][128][64] ----------
__global__ __launch_bounds__(256) void convert_x_kernel(
    const float* __restrict__ x, short* __restrict__ xb)
{
  int idx = blockIdx.x * 256 + threadIdx.x;     // 524288 total
  int t = idx >> 7;
  int h0 = (idx & 127) << 3;
  const float* src = x + (size_t)t * H_DIM + h0;
  float4 a = *(const float4*)src;
  float4 b = *(const float4*)(src + 4);
  s16x8 v;
  v[0] = f2b(a.x); v[1] = f2b(a.y); v[2] = f2b(a.z); v[3] = f2b(a.w);
  v[4] = f2b(b.x); v[5] = f2b(b.y); v[6] = f2b(b.z); v[7] = f2b(b.w);
  int rb = t >> 8, kt = h0 >> 6, half = (t >> 7) & 1;
  size_t off = ((size_t)((rb * 16 + kt) * 2 + half)) * 8192
             + (size_t)(t & 127) * 64 + (h0 & 63);
  *(s16x8*)(xb + off) = v;
}

// ---------- W1 [E][H][I] -> W1t panels per e: rows=i, k=h ----------
__global__ __launch_bounds__(256) void trans_w1_kernel(
    const float* __restrict__ W1, short* __restrict__ W1t)
{
  __shared__ short tile[64][65];            // [h][i]
  const int e = blockIdx.z;
  const int i0 = blockIdx.x * 64, h0 = blockIdx.y * 64;
  const int tid = threadIdx.x, c = tid & 63, r0 = tid >> 6;
  const float* src = W1 + ((size_t)e * H_DIM + h0) * I_DIM + i0;
#pragma unroll
  for (int j = 0; j < 16; ++j) {
    int r = j * 4 + r0;
    tile[r][c] = f2b(src[(size_t)r * I_DIM + c]);
  }
  __syncthreads();
  const int i = tid & 63, kq = tid >> 6;
  const size_t base = ((size_t)((e * 16 + (i0 >> 8)) * 16 + (h0 >> 6)) * 2
                       + ((i0 >> 7) & 1)) * 8192
                    + (size_t)((i0 & 64) + i) * 64;
#pragma unroll
  for (int w = 0; w < 2; ++w) {
    int kcl = kq + w * 4;                    // h-chunk 0..7
    s16x8 v;
#pragma unroll
    for (int j = 0; j < 8; ++j) v[j] = tile[kcl * 8 + j][i];
    *(s16x8*)(W1t + base + kcl * 8) = v;
  }
}

// ---------- W2 [E][I][H] -> W2t panels: rows=h, k=e*I+i ----------
__global__ __launch_bounds__(256) void trans_w2_kernel(
    const float* __restrict__ W2, short* __restrict__ W2t)
{
  __shared__ short tile[64][65];            // [i][h]
  const int e = blockIdx.z;
  const int i0 = blockIdx.x * 64, h0 = blockIdx.y * 64;
  const int tid = threadIdx.x, c = tid & 63, r0 = tid >> 6;
  const float* src = W2 + ((size_t)e * I_DIM + i0) * H_DIM + h0;
#pragma unroll
  for (int j = 0; j < 16; ++j) {
    int r = j * 4 + r0;
    tile[r][c] = f2b(src[(size_t)r * H_DIM + c]);
  }
  __syncthreads();
  const int h = tid & 63, kq = tid >> 6;
  const size_t base = ((size_t)((h0 >> 8) * 512 + e * 64 + (i0 >> 6)) * 2
                       + ((h0 >> 7) & 1)) * 8192
                    + (size_t)((h0 & 64) + h) * 64;
#pragma unroll
  for (int w = 0; w < 2; ++w) {
    int kcl = kq + w * 4;                    // i-chunk 0..7
    s16x8 v;
#pragma unroll
    for (int j = 0; j < 8; ++j) v[j] = tile[kcl * 8 + j][h];
    *(s16x8*)(W2t + base + kcl * 8) = v;
  }
}

// ================= 256x256xBK64 8-phase GEMM core =================
// 512 threads = 8 waves (2M x 4N); per-wave C = 128(M) x 64(N).
// LDS 128 KiB: A[2buf][2half][128][64] then B same at +64 KiB.
// Balanced phase loads: phase 0 = 8 B-reads (pinned for the K-tile) +
// 4 A-reads; phases 1-3 = 4 A-reads each. 16 MFMA per phase.
// Staging permutation obeys issue-after-last-read per chunk:
//   ph0,1: A(v)->buf1   (buf1-A last read: prev ph7)
//   ph2,3: B(u+2)->buf0 (buf0-B last read: ph0)
//   ph4,5: A(u+2)->buf0 (buf0-A last read: ph3)
//   ph6,7: B(v+2)->buf1 (buf1-B last read: ph4)
// Gates: end-ph3 vmcnt(4) (keeps B(u+2) in flight, drains B(v)+A(v));
//        end-ph7 vmcnt(4) (keeps B(v+2), drains B(u+2)+A(u+2)).

#define BARR()  __builtin_amdgcn_s_barrier()
#define FENCE() asm volatile("" ::: "memory")
#define LGKM0() do { asm volatile("s_waitcnt lgkmcnt(0)" ::: "memory"); \
                     __builtin_amdgcn_sched_barrier(0); } while (0)
#define VMC(N)  asm volatile("s_waitcnt vmcnt(" #N ")" ::: "memory")
#define PRIO1() __builtin_amdgcn_s_setprio(1)
#define PRIO0() __builtin_amdgcn_s_setprio(0)
#define SCHEDB() __builtin_amdgcn_sched_barrier(0)
#define MF(A, B, C) __builtin_amdgcn_mfma_f32_16x16x32_bf16(A, B, C, 0, 0, 0)

__device__ __forceinline__ void gemm_core(
    const short* __restrict__ Ag, const short* __restrict__ Bg,
    int nk, short* lds, f32x4 acc[8][4])
{
  const int tid  = threadIdx.x;
  const int wave = tid >> 6, lane = tid & 63;
  const int wm = wave >> 2, wn = wave & 3;
  const int g = lane >> 4, r16 = lane & 15;

  // stage-source swizzled offsets (shorts): L ^ (((L>>7)&7)<<4)
  const int L0 = tid * 16;
  const int L1 = 8192 + tid * 16;
  const int s0 = (L0 ^ (((L0 >> 7) & 7) << 4)) >> 1;
  const int s1 = (L1 ^ (((L1 >> 7) & 7) << 4)) >> 1;

  short* stA = lds + wave * 512;            // per-wave 1 KiB slice
  short* stB = lds + 32768 + wave * 512;

  // ds_read per-lane offsets (shorts), same XOR swizzle
  const int xr_ = (r16 & 7) << 4;
  const int rd0 = r16 * 64 + ((((0 << 6) | (g << 4)) ^ xr_) >> 1);
  const int rd1 = r16 * 64 + ((((1 << 6) | (g << 4)) ^ xr_) >> 1);

  const short* Ah = lds + wm * 8192;
  const short* Bh = lds + 32768 + (wn >> 1) * 8192 + (wn & 1) * 4096;

  s16x8 bf[8];             // B pinned per K-tile: bf[n*2+kh]
  s16x8 a0, a1, a2, a3;    // streamed A m-pair for the current phase

#define STAGE_A(KT, HH, BUF) do { \
    const short* _s = Ag + (size_t)(KT) * 16384 + (HH) * 8192; \
    short* _d = stA + ((BUF) * 2 + (HH)) * 8192; \
    gld_lds16(_d, _s + s0); \
    gld_lds16(_d + 4096, _s + s1); } while (0)
#define STAGE_B(KT, HH, BUF) do { \
    const short* _s = Bg + (size_t)(KT) * 16384 + (HH) * 8192; \
    short* _d = stB + ((BUF) * 2 + (HH)) * 8192; \
    gld_lds16(_d, _s + s0); \
    gld_lds16(_d + 4096, _s + s1); } while (0)
#define LDB_ALL(BUF) \
    _Pragma("unroll") \
    for (int n = 0; n < 4; ++n) { \
      bf[n * 2]     = *(const s16x8*)(Bh + (BUF) * 16384 + n * 1024 + rd0); \
      bf[n * 2 + 1] = *(const s16x8*)(Bh + (BUF) * 16384 + n * 1024 + rd1); }
#define LDA_PAIR(BUF, P) do { \
    a0 = *(const s16x8*)(Ah + (BUF) * 16384 + (2 * (P)) * 1024 + rd0); \
    a1 = *(const s16x8*)(Ah + (BUF) * 16384 + (2 * (P)) * 1024 + rd1); \
    a2 = *(const s16x8*)(Ah + (BUF) * 16384 + (2 * (P) + 1) * 1024 + rd0); \
    a3 = *(const s16x8*)(Ah + (BUF) * 16384 + (2 * (P) + 1) * 1024 + rd1); } while (0)
#define MFMA_PAIR(P) \
    _Pragma("unroll") \
    for (int n = 0; n < 4; ++n) { \
      acc[2 * (P)][n]     = MF(a0, bf[n * 2],     acc[2 * (P)][n]); \
      acc[2 * (P)][n]     = MF(a1, bf[n * 2 + 1], acc[2 * (P)][n]); \
      acc[2 * (P) + 1][n] = MF(a2, bf[n * 2],     acc[2 * (P) + 1][n]); \
      acc[2 * (P) + 1][n] = MF(a3, bf[n * 2 + 1], acc[2 * (P) + 1][n]); }

  // prologue: buf0 = tile0 (A+B); buf1 = B(tile1). A(tile1) is staged in
  // iteration 0 phases 0-1. vmcnt(4) keeps B(1) (4 loads) in flight.
  STAGE_A(0, 0, 0); STAGE_A(0, 1, 0); STAGE_B(0, 0, 0); STAGE_B(0, 1, 0);
  STAGE_B(1, 0, 1); STAGE_B(1, 1, 1);
  VMC(4);
  BARR(); FENCE();

  const int iters = nk >> 1;
  for (int it = 0; it < iters; ++it) {
    const int u = it * 2, v = u + 1;
    const bool nlast = (it + 1 < iters);

    // ---- K-tile u (buffer 0): phases 0-3 ----
    LDB_ALL(0); LDA_PAIR(0, 0);
    STAGE_A(v, 0, 1);
    BARR(); LGKM0();
    PRIO1(); MFMA_PAIR(0); PRIO0();
    SCHEDB(); BARR(); FENCE();

    LDA_PAIR(0, 1);
    STAGE_A(v, 1, 1);
    BARR(); LGKM0();
    PRIO1(); MFMA_PAIR(1); PRIO0();
    SCHEDB(); BARR(); FENCE();

    LDA_PAIR(0, 2);
    if (nlast) STAGE_B(u + 2, 0, 0);
    BARR(); LGKM0();
    PRIO1(); MFMA_PAIR(2); PRIO0();
    SCHEDB(); BARR(); FENCE();

    LDA_PAIR(0, 3);
    if (nlast) STAGE_B(u + 2, 1, 0);
    BARR(); LGKM0();
    PRIO1(); MFMA_PAIR(3); PRIO0();
    if (nlast) { VMC(4); } else { VMC(0); }   // A(v)+B(v) fully resident
    SCHEDB(); BARR(); FENCE();

    // ---- K-tile v (buffer 1): phases 4-7 ----
    LDB_ALL(1); LDA_PAIR(1, 0);
    if (nlast) STAGE_A(u + 2, 0, 0);
    BARR(); LGKM0();
    PRIO1(); MFMA_PAIR(0); PRIO0();
    SCHEDB(); BARR(); FENCE();

    LDA_PAIR(1, 1);
    if (nlast) STAGE_A(u + 2, 1, 0);
    BARR(); LGKM0();
    PRIO1(); MFMA_PAIR(1); PRIO0();
    SCHEDB(); BARR(); FENCE();

    LDA_PAIR(1, 2);
    if (nlast) STAGE_B(v + 2, 0, 1);
    BARR(); LGKM0();
    PRIO1(); MFMA_PAIR(2); PRIO0();
    SCHEDB(); BARR(); FENCE();

    LDA_PAIR(1, 3);
    if (nlast) STAGE_B(v + 2, 1, 1);
    BARR(); LGKM0();
    PRIO1(); MFMA_PAIR(3); PRIO0();
    if (nlast) VMC(4);                        // B(u+2)+A(u+2) resident
    SCHEDB(); BARR(); FENCE();
  }
#undef STAGE_A
#undef STAGE_B
#undef LDB_ALL
#undef LDA_PAIR
#undef MFMA_PAIR
}

// ---------- GEMM1: h = gelu(W1^T-tile x x-tile + b1) * gate -> hg panels ----------
// A = W1t (rows=i), B = xb (rows=t): D row = i (4 consecutive per lane).
__global__ __launch_bounds__(512) void gemm1_kernel(
    const short* __restrict__ xb, const short* __restrict__ W1t,
    const float* __restrict__ b1, const float* __restrict__ gate,
    short* __restrict__ hg)
{
  extern __shared__ short lds[];
  const int bi = blockIdx.x, bt = blockIdx.y, e = blockIdx.z;
  f32x4 acc[8][4];
#pragma unroll
  for (int i = 0; i < 8; ++i)
#pragma unroll
    for (int j = 0; j < 4; ++j) acc[i][j] = (f32x4){0.f, 0.f, 0.f, 0.f};

  const short* Ag = W1t + (size_t)(e * 16 + bi) * 16 * 16384;
  const short* Bg = xb + (size_t)bt * 16 * 16384;
  gemm_core(Ag, Bg, 16, lds, acc);

  const int tid = threadIdx.x, wave = tid >> 6, lane = tid & 63;
  const int wm = wave >> 2, wn = wave & 3, g = lane >> 4, r16 = lane & 15;
#pragma unroll
  for (int mg = 0; mg < 8; ++mg) {
    const int i4 = bi * 256 + wm * 128 + mg * 16 + g * 4;   // 4 consecutive i
    const float4 b1v = *(const float4*)(b1 + e * I_DIM + i4);
    const int kt = (e * I_DIM + i4) >> 6;
    const int c = i4 & 63;
    short* dst = hg + ((size_t)(bt * 512 + kt) * 2 + (wn >> 1)) * 8192 + c;
#pragma unroll
    for (int ng = 0; ng < 4; ++ng) {
      const int tl = wn * 64 + ng * 16 + r16;               // t within tile
      const float gt = gate[(bt * 256 + tl) * E_NUM + e];
      const float v0 = gelu_f(acc[mg][ng][0] + b1v.x) * gt;
      const float v1 = gelu_f(acc[mg][ng][1] + b1v.y) * gt;
      const float v2 = gelu_f(acc[mg][ng][2] + b1v.z) * gt;
      const float v3 = gelu_f(acc[mg][ng][3] + b1v.w) * gt;
      int2 pk;
      pk.x = (int)((unsigned)f2b(v0) | ((unsigned)f2b(v1) << 16));
      pk.y = (int)((unsigned)f2b(v2) | ((unsigned)f2b(v3) << 16));
      *(int2*)(dst + (size_t)(tl & 127) * 64) = pk;
    }
  }
}

// ---------- GEMM2: part[ks] = hg-tile @ W2-tile (split-K=4, no atomics) ----------
// A = W2t (rows=h), B = hg (rows=t): D row = h (float4 stores).
__global__ __launch_bounds__(512) void gemm2_kernel(
    const short* __restrict__ W2t, const short* __restrict__ hg,
    float* __restrict__ part)
{
  extern __shared__ short lds[];
  const int bh = blockIdx.x, bt = blockIdx.y, ks = blockIdx.z;
  f32x4 acc[8][4];
#pragma unroll
  for (int i = 0; i < 8; ++i)
#pragma unroll
    for (int j = 0; j < 4; ++j) acc[i][j] = (f32x4){0.f, 0.f, 0.f, 0.f};

  const short* Ag = W2t + (size_t)(bh * 512 + ks * 128) * 16384;
  const short* Bg = hg  + (size_t)(bt * 512 + ks * 128) * 16384;
  gemm_core(Ag, Bg, 128, lds, acc);

  const int tid = threadIdx.x, wave = tid >> 6, lane = tid & 63;
  const int wm = wave >> 2, wn = wave & 3, g = lane >> 4, r16 = lane & 15;
  float* dst = part + (size_t)ks * ((size_t)T_TOK * H_DIM);
#pragma unroll
  for (int mg = 0; mg < 8; ++mg) {
    const int h4 = bh * 256 + wm * 128 + mg * 16 + g * 4;   // 4 consecutive h
#pragma unroll
    for (int ng = 0; ng < 4; ++ng) {
      const int t = bt * 256 + wn * 64 + ng * 16 + r16;
      *(f32x4*)(dst + (size_t)t * H_DIM + h4) = acc[mg][ng];
    }
  }
}

// ---------- reduce: out = sum_ks part[ks] + sum_e gate*b2 ----------
__global__ __launch_bounds__(256) void reduce_kernel(
    const float* __restrict__ part, const float* __restrict__ gate,
    const float* __restrict__ b2, float* __restrict__ out)
{
  const int idx = blockIdx.x * 256 + threadIdx.x;   // 1M threads, float4 each
  const int t = idx >> 8;
  const int h4 = (idx & 255) << 2;
  const size_t off = (size_t)t * H_DIM + h4;
  const size_t SL = (size_t)T_TOK * H_DIM;
  float4 a0 = *(const float4*)(part + off);
  float4 a1 = *(const float4*)(part + SL + off);
  float4 a2 = *(const float4*)(part + 2 * SL + off);
  float4 a3 = *(const float4*)(part + 3 * SL + off);
  float sx = a0.x + a1.x + a2.x + a3.x;
  float sy = a0.y + a1.y + a2.y + a3.y;
  float sz = a0.z + a1.z + a2.z + a3.z;
  float sw = a0.w + a1.w + a2.w + a3.w;
#pragma unroll
  for (int e = 0; e < E_NUM; ++e) {
    const float gv = gate[t * E_NUM + e];
    const float4 bv = *(const float4*)(b2 + e * H_DIM + h4);
    sx = fmaf(gv, bv.x, sx); sy = fmaf(gv, bv.y, sy);
    sz = fmaf(gv, bv.z, sz); sw = fmaf(gv, bv.w, sw);
  }
  float4 r; r.x = sx; r.y = sy; r.z = sz; r.w = sw;
  *(float4*)(out + off) = r;
}

// ---------- launch ----------
extern "C" void kernel_launch(void* const* d_in, const int* in_sizes, int n_in,
                              void* d_out, int out_size, void* d_ws, size_t ws_size,
                              hipStream_t stream) {
  const float* x  = (const float*)d_in[0];
  const float* Wg = (const float*)d_in[1];
  const float* W1 = (const float*)d_in[2];
  const float* b1 = (const float*)d_in[3];
  const float* W2 = (const float*)d_in[4];
  const float* b2 = (const float*)d_in[5];
  float* out = (float*)d_out;

  char* ws = (char*)d_ws;
  float* gate = (float*)ws;                                    // 128 KiB
  short* xb   = (short*)(ws + 131072);                         // 8 MiB
  short* W1t  = (short*)(ws + 131072 + 8388608);               // 64 MiB
  short* W2t  = (short*)(ws + 131072 + 8388608 + 67108864);    // 64 MiB
  short* hg   = (short*)(ws + 131072 + 8388608 + 2 * 67108864);// 256 MiB
  // part aliases xb+W1t (both dead after gemm1): 64 MiB
  float* part = (float*)(ws + 131072);

  static bool attr_done = false;
  if (!attr_done) {
    hipFuncSetAttribute((const void*)gemm1_kernel,
                        hipFuncAttributeMaxDynamicSharedMemorySize, 131072);
    hipFuncSetAttribute((const void*)gemm2_kernel,
                        hipFuncAttributeMaxDynamicSharedMemorySize, 131072);
    attr_done = true;
  }

  gate_kernel<<<T_TOK / 4, 256, 0, stream>>>(x, Wg, gate);
  convert_x_kernel<<<2048, 256, 0, stream>>>(x, xb);
  trans_w1_kernel<<<dim3(I_DIM / 64, H_DIM / 64, E_NUM), 256, 0, stream>>>(W1, W1t);
  trans_w2_kernel<<<dim3(I_DIM / 64, H_DIM / 64, E_NUM), 256, 0, stream>>>(W2, W2t);
  gemm1_kernel<<<dim3(16, 16, 8), 512, 131072, stream>>>(xb, W1t, b1, gate, hg);
  gemm2_kernel<<<dim3(4, 16, 4), 512, 131072, stream>>>(W2t, hg, part);
  reduce_kernel<<<4096, 256, 0, stream>>>(part, gate, b2, out);
}